// Round 1
// baseline (85.908 us; speedup 1.0000x reference)
//
#include <hip/hip_runtime.h>
#include <stdint.h>

// GraphPool: out[s,a,f] = max over {self, valid neighbors} atoms[s,idx,f],
// zeroed when atom has no valid neighbors. S=512, A=128, F=128, D=6.
//
// v2: persistent per-s blocks with a 2-deep LDS pipeline.
//   - One block per s (grid 512, 512 threads, 2 blocks/CU, 36 KB LDS).
//   - Edges read + precomputed ONCE per s (was 4x, one per feature quarter).
//   - Quarter-slab staging double-buffered: __syncthreads() drains stage(q)
//     (issued one full gather-phase earlier -> latency hidden), THEN stage(q+1)
//     is issued, THEN gather(q) runs. The prefetch is never drained by the
//     barrier that follows its own issue, so stage(q+1) overlaps gather(q)
//     and the out-stores of quarter q (reads+writes interleave at HBM).
//   - Gather layout unchanged: unpadded 128 B LDS rows -> bank-uniform
//     b128 gather (row*128 B keeps bank = f(quad) only; 8 accesses/bank
//     is the b128 minimum, distinct rows add no extra serialization).

constexpr int S  = 512;
constexpr int A  = 128;
constexpr int F  = 128;
constexpr int D  = 6;
constexpr int QF = 32;              // features per quarter-tile
constexpr int ROWB = QF * 4;        // LDS row bytes = 128
constexpr int NT = 512;             // threads per block (8 waves)

#define GLOBAL_AS __attribute__((address_space(1)))
#define LDS_AS    __attribute__((address_space(3)))

__global__ __launch_bounds__(NT, 4) void graphpool_kernel(
    const float* __restrict__ atoms,   // (S, A, F)
    const int*   __restrict__ edges,   // (S, A, D), -1 = padding
    float*       __restrict__ out)     // (S, A, F)
{
    __shared__ __align__(16) float sl[2][A * QF];  // 2 x 16 KB quarter slabs
    __shared__ __align__(16) int   se[A * 8];      // 4 KB: off0..off5, mask, pad

    const int tid  = threadIdx.x;
    const int s    = blockIdx.x;
    const int wave = tid >> 6;
    const int lane = tid & 63;

    const float* sbase = atoms + (size_t)s * (A * F);
    // chunk = 8 rows x 32 floats (1 KB); lane l -> row l>>3, quad col l&7;
    // LDS dest = uniform chunk base + 16*lane (global_load_lds contract).
    const int rowq = lane >> 3;
    const int colq = lane & 7;

    // ---- prologue: stage quarter 0 (16 chunks, 2 per wave) ----
#pragma unroll
    for (int i = 0; i < 2; ++i) {
        const int chunk = wave * 2 + i;
        const float* gp = sbase + (size_t)(chunk * 8 + rowq) * F + colq * 4;
        float* lp = &sl[0][chunk * 256];           // wave-uniform base
        __builtin_amdgcn_global_load_lds((const GLOBAL_AS float*)gp,
                                         (LDS_AS float*)lp, 16, 0, 0);
    }

    // ---- edge precompute, ONCE per s: thread t < 128 handles atom t ----
    if (tid < A) {
        const int* eg = edges + ((size_t)s * A + tid) * D;
        const int i0 = eg[0], i1 = eg[1], i2 = eg[2];
        const int i3 = eg[3], i4 = eg[4], i5 = eg[5];
        const int deg = (i0 >= 0) + (i1 >= 0) + (i2 >= 0) +
                        (i3 >= 0) + (i4 >= 0) + (i5 >= 0);
        const int self = tid * ROWB;               // byte offset of own row
        int4 w0, w1;
        w0.x = (i0 >= 0) ? i0 * ROWB : self;
        w0.y = (i1 >= 0) ? i1 * ROWB : self;
        w0.z = (i2 >= 0) ? i2 * ROWB : self;
        w0.w = (i3 >= 0) ? i3 * ROWB : self;
        w1.x = (i4 >= 0) ? i4 * ROWB : self;
        w1.y = (i5 >= 0) ? i5 * ROWB : self;
        w1.z = __float_as_int(deg ? 1.0f : 0.0f);
        w1.w = 0;
        *(int4*)&se[tid * 8]     = w0;
        *(int4*)&se[tid * 8 + 4] = w1;
    }

    const int q8   = tid & 7;
    const int qoff = q8 * 16;                      // byte offset within row
    float* orow = out + (size_t)s * (A * F) + q8 * 4;

#pragma unroll
    for (int q = 0; q < 4; ++q) {
        // Drains stage(q) (+ se writes on q==0). Also guarantees every wave
        // finished reading sl[(q+1)&1] in iteration q-1, so it is safe to
        // overwrite it below. stage(q) had the whole gather(q-1) phase to
        // complete, so this drain is cheap except at q==0.
        __syncthreads();

        if (q < 3) {   // issue prefetch of quarter q+1 into the other buffer
            const float* slab = sbase + (size_t)(q + 1) * QF;
#pragma unroll
            for (int i = 0; i < 2; ++i) {
                const int chunk = wave * 2 + i;
                const float* gp = slab + (size_t)(chunk * 8 + rowq) * F + colq * 4;
                float* lp = &sl[(q + 1) & 1][chunk * 256];
                __builtin_amdgcn_global_load_lds((const GLOBAL_AS float*)gp,
                                                 (LDS_AS float*)lp, 16, 0, 0);
            }
        }

        // ---- gather quarter q: 512 threads x 2 passes = 128 atoms x 8 quads
        const char* lbase = (const char*)sl[q & 1];
        float* outq = orow + q * QF;

#pragma unroll
        for (int p = 0; p < 2; ++p) {
            const int a = p * 64 + (tid >> 3);

            const int4 e0 = *(const int4*)&se[a * 8];
            const int4 e1 = *(const int4*)&se[a * 8 + 4];
            const float maskf = __int_as_float(e1.z);

            float4 m = *(const float4*)(lbase + a * ROWB + qoff);  // self
            float4 v;
            v = *(const float4*)(lbase + e0.x + qoff);
            m.x = fmaxf(m.x, v.x); m.y = fmaxf(m.y, v.y);
            m.z = fmaxf(m.z, v.z); m.w = fmaxf(m.w, v.w);
            v = *(const float4*)(lbase + e0.y + qoff);
            m.x = fmaxf(m.x, v.x); m.y = fmaxf(m.y, v.y);
            m.z = fmaxf(m.z, v.z); m.w = fmaxf(m.w, v.w);
            v = *(const float4*)(lbase + e0.z + qoff);
            m.x = fmaxf(m.x, v.x); m.y = fmaxf(m.y, v.y);
            m.z = fmaxf(m.z, v.z); m.w = fmaxf(m.w, v.w);
            v = *(const float4*)(lbase + e0.w + qoff);
            m.x = fmaxf(m.x, v.x); m.y = fmaxf(m.y, v.y);
            m.z = fmaxf(m.z, v.z); m.w = fmaxf(m.w, v.w);
            v = *(const float4*)(lbase + e1.x + qoff);
            m.x = fmaxf(m.x, v.x); m.y = fmaxf(m.y, v.y);
            m.z = fmaxf(m.z, v.z); m.w = fmaxf(m.w, v.w);
            v = *(const float4*)(lbase + e1.y + qoff);
            m.x = fmaxf(m.x, v.x); m.y = fmaxf(m.y, v.y);
            m.z = fmaxf(m.z, v.z); m.w = fmaxf(m.w, v.w);

            m.x *= maskf; m.y *= maskf; m.z *= maskf; m.w *= maskf;

            *(float4*)(outq + (size_t)a * F) = m;
        }
    }
}

extern "C" void kernel_launch(void* const* d_in, const int* in_sizes, int n_in,
                              void* d_out, int out_size, void* d_ws, size_t ws_size,
                              hipStream_t stream) {
    const float* atoms = (const float*)d_in[0];
    const int*   edges = (const int*)d_in[1];
    float*       out   = (float*)d_out;

    graphpool_kernel<<<S, NT, 0, stream>>>(atoms, edges, out);
}

// Round 2
// 83.779 us; speedup vs baseline: 1.0254x; 1.0254x over previous
//
#include <hip/hip_runtime.h>
#include <stdint.h>

// GraphPool: out[s,a,f] = max over {self, valid neighbors} atoms[s,idx,f],
// zeroed when atom has no valid neighbors. S=512, A=128, F=128, D=6.
//
// v3 == v1 (reverted): one block per (s, feature-quarter), 2048 blocks,
// 8 blocks/CU. Round-1 A/B showed the persistent double-buffered variant
// (v2: 512 blocks, 2/CU, 1x edge reads) measures within noise of this —
// the kernel is at its ~69 MB traffic floor (~11-12 us at 6.3 TB/s) and
// the bench total is dominated by the harness's 268 MB poison fill
// (~43 us/iter) + input restores. Keeping the simpler, best-measured form.
//
// Structure: stage the 128x32 f32 slab via global_load_lds (async,
// width=16, unpadded 128 B rows -> bank-uniform b128 gather), precompute
// per-atom gather BYTE offsets + validity mask once, then a lean gather
// loop: 9 ds_read_b128 + fmax per pass.

constexpr int S  = 512;
constexpr int A  = 128;
constexpr int F  = 128;
constexpr int D  = 6;
constexpr int QF = 32;              // features per block
constexpr int ROWB = QF * 4;        // LDS row bytes = 128

#define GLOBAL_AS __attribute__((address_space(1)))
#define LDS_AS    __attribute__((address_space(3)))

__global__ __launch_bounds__(256, 8) void graphpool_kernel(
    const float* __restrict__ atoms,   // (S, A, F)
    const int*   __restrict__ edges,   // (S, A, D), -1 = padding
    float*       __restrict__ out)     // (S, A, F)
{
    __shared__ __align__(16) float sl[A * QF];  // 16 KB
    __shared__ __align__(16) int   se[A * 8];   // 4 KB: off0..off5, maskbits, pad

    const int tid  = threadIdx.x;
    const int qb   = blockIdx.x & 3;            // feature quarter
    const int s    = blockIdx.x >> 2;
    const int wave = tid >> 6;
    const int lane = tid & 63;

    // ---- async stage atoms quarter-slab: 16 chunks of 1 KB, 4 per wave ----
    // chunk = 8 rows x 32 floats; lane l -> row l>>3, quad col l&7;
    // LDS dest = uniform chunk base + 16*lane (global_load_lds contract).
    const float* slab = atoms + (size_t)s * (A * F) + qb * QF;
    {
        const int rowq = lane >> 3;
        const int colq = lane & 7;
#pragma unroll
        for (int i = 0; i < 4; ++i) {
            const int chunk = wave * 4 + i;
            const float* gp = slab + (size_t)(chunk * 8 + rowq) * F + colq * 4;
            float* lp = &sl[chunk * 256];       // wave-uniform base
            __builtin_amdgcn_global_load_lds((const GLOBAL_AS float*)gp,
                                             (LDS_AS float*)lp, 16, 0, 0);
        }
    }

    // ---- edge precompute: thread t < 128 handles atom t ----
    if (tid < A) {
        const int* eg = edges + ((size_t)s * A + tid) * D;
        const int i0 = eg[0], i1 = eg[1], i2 = eg[2];
        const int i3 = eg[3], i4 = eg[4], i5 = eg[5];
        const int deg = (i0 >= 0) + (i1 >= 0) + (i2 >= 0) +
                        (i3 >= 0) + (i4 >= 0) + (i5 >= 0);
        const int self = tid * ROWB;            // byte offset of own row
        int4 w0, w1;
        w0.x = (i0 >= 0) ? i0 * ROWB : self;
        w0.y = (i1 >= 0) ? i1 * ROWB : self;
        w0.z = (i2 >= 0) ? i2 * ROWB : self;
        w0.w = (i3 >= 0) ? i3 * ROWB : self;
        w1.x = (i4 >= 0) ? i4 * ROWB : self;
        w1.y = (i5 >= 0) ? i5 * ROWB : self;
        w1.z = __float_as_int(deg ? 1.0f : 0.0f);
        w1.w = 0;
        *(int4*)&se[tid * 8]     = w0;
        *(int4*)&se[tid * 8 + 4] = w1;
    }

    __syncthreads();   // drains vmcnt (global_load_lds) + lgkmcnt

    // ---- gather: 256 threads x 4 passes cover 128 atoms x 8 quads ----
    const int q    = tid & 7;
    const int qoff = q * 16;                    // byte offset within row
    const char* lbase = (const char*)sl;
    float* outb = out + (size_t)s * (A * F) + qb * QF + q * 4;

#pragma unroll
    for (int p = 0; p < 4; ++p) {
        const int a = p * 32 + (tid >> 3);

        const int4 e0 = *(const int4*)&se[a * 8];
        const int4 e1 = *(const int4*)&se[a * 8 + 4];
        const float maskf = __int_as_float(e1.z);

        float4 m = *(const float4*)(lbase + a * ROWB + qoff);  // self
        float4 v;
        v = *(const float4*)(lbase + e0.x + qoff);
        m.x = fmaxf(m.x, v.x); m.y = fmaxf(m.y, v.y);
        m.z = fmaxf(m.z, v.z); m.w = fmaxf(m.w, v.w);
        v = *(const float4*)(lbase + e0.y + qoff);
        m.x = fmaxf(m.x, v.x); m.y = fmaxf(m.y, v.y);
        m.z = fmaxf(m.z, v.z); m.w = fmaxf(m.w, v.w);
        v = *(const float4*)(lbase + e0.z + qoff);
        m.x = fmaxf(m.x, v.x); m.y = fmaxf(m.y, v.y);
        m.z = fmaxf(m.z, v.z); m.w = fmaxf(m.w, v.w);
        v = *(const float4*)(lbase + e0.w + qoff);
        m.x = fmaxf(m.x, v.x); m.y = fmaxf(m.y, v.y);
        m.z = fmaxf(m.z, v.z); m.w = fmaxf(m.w, v.w);
        v = *(const float4*)(lbase + e1.x + qoff);
        m.x = fmaxf(m.x, v.x); m.y = fmaxf(m.y, v.y);
        m.z = fmaxf(m.z, v.z); m.w = fmaxf(m.w, v.w);
        v = *(const float4*)(lbase + e1.y + qoff);
        m.x = fmaxf(m.x, v.x); m.y = fmaxf(m.y, v.y);
        m.z = fmaxf(m.z, v.z); m.w = fmaxf(m.w, v.w);

        m.x *= maskf; m.y *= maskf; m.z *= maskf; m.w *= maskf;

        *(float4*)(outb + (size_t)a * F) = m;
    }
}

extern "C" void kernel_launch(void* const* d_in, const int* in_sizes, int n_in,
                              void* d_out, int out_size, void* d_ws, size_t ws_size,
                              hipStream_t stream) {
    const float* atoms = (const float*)d_in[0];
    const int*   edges = (const int*)d_in[1];
    float*       out   = (float*)d_out;

    graphpool_kernel<<<S * 4, 256, 0, stream>>>(atoms, edges, out);
}